// Round 6
// baseline (1679.986 us; speedup 1.0000x reference)
//
#include <hip/hip_runtime.h>
#include <stdint.h>

#define N_ROWS 65536
#define K_DIM  1024
#define J_OUT  256
#define BM 128
#define BN 512
#define BK 32
#define NT (K_DIM / BK)   // 32 K-steps
#define THREADS 512       // 8 waves: 2 wave-rows x 4 wave-cols

typedef _Float16 half8 __attribute__((ext_vector_type(8)));
typedef float    f32x4 __attribute__((ext_vector_type(4)));

// ---------------- threefry2x32, key=(0,42) — partitionable, XOR-fold -------
// bits1,bits2 = threefry2x32(k1=0,k2=42, x0=hi32(i)=0, x1=lo32(i)=i);
// 32-bit draw = bits1 ^ bits2.  (Verified: passed R5.)
__device__ __forceinline__ uint32_t tf_bits_xor(uint32_t ctr) {
  const uint32_t ks0 = 0u, ks1 = 42u, ks2 = 0x1BD11BF0u; // 0x1BD11BDA ^ 0 ^ 42
  uint32_t x0 = 0u;          // counts_hi + ks0
  uint32_t x1 = ctr + ks1;   // counts_lo + ks1
#define TF_R(rr) x0 += x1; x1 = ((x1 << rr) | (x1 >> (32 - rr))) ^ x0;
  TF_R(13) TF_R(15) TF_R(26) TF_R(6)
  x0 += ks1; x1 += ks2 + 1u;
  TF_R(17) TF_R(29) TF_R(16) TF_R(24)
  x0 += ks2; x1 += ks0 + 2u;
  TF_R(13) TF_R(15) TF_R(26) TF_R(6)
  x0 += ks0; x1 += ks1 + 3u;
  TF_R(17) TF_R(29) TF_R(16) TF_R(24)
  x0 += ks1; x1 += ks2 + 4u;
  TF_R(13) TF_R(15) TF_R(26) TF_R(6)
  x0 += ks2; x1 += ks0 + 5u;
#undef TF_R
  return x0 ^ x1;
}

// uniform(lo=nextafter(-1,0), hi=1) then sqrt(2)*erfinv (XLA Giles polynomial)
__device__ __forceinline__ float eps_from_bits(uint32_t bits) {
  float f = __uint_as_float((bits >> 9) | 0x3F800000u) - 1.0f;   // [0,1)
  float u = fmaxf(-0.99999994f, f * 2.0f - 0.99999994f);
  float w = -log1pf(-u * u);
  float p;
  if (w < 5.0f) {
    w = w - 2.5f;
    p = 2.81022636e-08f;
    p = fmaf(p, w, 3.43273939e-07f);
    p = fmaf(p, w, -3.5233877e-06f);
    p = fmaf(p, w, -4.39150654e-06f);
    p = fmaf(p, w, 0.00021858087f);
    p = fmaf(p, w, -0.00125372503f);
    p = fmaf(p, w, -0.00417768164f);
    p = fmaf(p, w, 0.246640727f);
    p = fmaf(p, w, 1.50140941f);
  } else {
    w = sqrtf(w) - 3.0f;
    p = -0.000200214257f;
    p = fmaf(p, w, 0.000100950558f);
    p = fmaf(p, w, 0.00134934322f);
    p = fmaf(p, w, -0.00367342844f);
    p = fmaf(p, w, 0.00573950773f);
    p = fmaf(p, w, -0.0076224613f);
    p = fmaf(p, w, -0.00943887047f);
    p = fmaf(p, w, 1.00167406f);
    p = fmaf(p, w, 2.83297682f);
  }
  return 1.41421354f * (p * u);
}

// ---------------- W pre-pack: f32 -> f16, fused/interleaved/swizzled -------
// wt halves layout: [t (32 K-tiles)][j (512)][s (4 slots of 8 halves)]
//   fused col j: h=(j>>4)&1 selects head, c=(j>>5)*16+(j&15)
//   slot s holds k-range for ks = s ^ ((j>>1)&3)  (XOR swizzle -> 2-way free)
__global__ void pack_w_kernel(const float* __restrict__ Wmu,
                              const float* __restrict__ Wls,
                              _Float16* __restrict__ wt) {
  const int chunk = blockIdx.x * blockDim.x + threadIdx.x;  // 0..65535
  const int s = chunk & 3;
  const int j = (chunk >> 2) & 511;
  const int t = chunk >> 11;
  const int ks = s ^ ((j >> 1) & 3);
  const int k0 = t * 32 + ks * 8;
  const int h = (j >> 4) & 1;
  const int c = ((j >> 5) << 4) | (j & 15);
  const float* W = h ? Wls : Wmu;
  half8 v;
#pragma unroll
  for (int e = 0; e < 8; ++e) v[e] = (_Float16)W[(size_t)(k0 + e) * J_OUT + c];
  *(half8*)(wt + (size_t)chunk * 8) = v;
}

// ---------------- fused GEMM + heads + sampling ----------------------------
__global__ __launch_bounds__(THREADS, 2)
void fused_heads_kernel(const float* __restrict__ x,
                        const _Float16* __restrict__ wt,
                        const float* __restrict__ b_mu,
                        const float* __restrict__ b_ls,
                        float* __restrict__ out) {
  __shared__ __align__(16) _Float16 Alds[2][BM][40];   // 20.5 KiB
  __shared__ __align__(16) _Float16 Blds[2][BN * BK];  // 64 KiB (epilogue reuses)
  const int tid  = threadIdx.x;
  const int lane = tid & 63;
  const int wv   = tid >> 6;        // wave 0..7
  const int wr   = wv >> 2;         // wave row 0..1  (64 output rows each)
  const int wc   = wv & 3;          // wave col 0..3  (64 output cols each)
  const int rowbase = blockIdx.x * BM;

  // A staging: thread -> (row, 8-float k-chunk);  128 rows x 4 chunks = 512
  const int arow  = tid >> 2;
  const int aslot = tid & 3;
  const float* aptr = x + (size_t)(rowbase + arow) * K_DIM + aslot * 8;
  const int awr_off = arow * 40 + aslot * 8;   // halves

  // fragment read offsets (halves)
  const int afrag_off = (wr * 64 + (lane & 15)) * 40 + (lane >> 4) * 8;     // +m*640
  const int bswz = (lane >> 4) ^ (((lane & 15) >> 1) & 3);
  const int bfrag_off = (wc * 128 + (lane & 15)) * 32 + bswz * 8;           // +n*512

  f32x4 acc[4][8] = {};

  // ---- prologue: stage tile 0 into buffer 0
  {
    half8 bs[4];
#pragma unroll
    for (int q = 0; q < 4; ++q) bs[q] = *(const half8*)(wt + q * 4096 + tid * 8);
    f32x4 a0 = *(const f32x4*)(aptr);
    f32x4 a1 = *(const f32x4*)(aptr + 4);
    half8 ah;
#pragma unroll
    for (int e = 0; e < 4; ++e) { ah[e] = (_Float16)a0[e]; ah[e + 4] = (_Float16)a1[e]; }
#pragma unroll
    for (int q = 0; q < 4; ++q) *(half8*)(&Blds[0][0] + q * 4096 + tid * 8) = bs[q];
    *(half8*)(&Alds[0][0][0] + awr_off) = ah;
  }
  __syncthreads();

  // ---- main K loop, double buffered, one barrier per K-step
  for (int t = 0; t < NT; ++t) {
    const int cur = t & 1;
    const bool more = (t + 1 < NT);
    half8 bs[4]; f32x4 a0, a1;
    if (more) {
      const _Float16* wsn = wt + (size_t)(t + 1) * 16384;
#pragma unroll
      for (int q = 0; q < 4; ++q) bs[q] = *(const half8*)(wsn + q * 4096 + tid * 8);
      a0 = *(const f32x4*)(aptr + (t + 1) * BK);
      a1 = *(const f32x4*)(aptr + (t + 1) * BK + 4);
    }

    const _Float16* Ab = &Alds[cur][0][0];
    const _Float16* Bb = &Blds[cur][0];
    half8 af[4], bf[8];
#pragma unroll
    for (int m = 0; m < 4; ++m) af[m] = *(const half8*)(Ab + m * 640 + afrag_off);
#pragma unroll
    for (int n = 0; n < 8; ++n) bf[n] = *(const half8*)(Bb + bfrag_off + n * 512);
#pragma unroll
    for (int m = 0; m < 4; ++m)
#pragma unroll
      for (int n = 0; n < 8; ++n)
        acc[m][n] = __builtin_amdgcn_mfma_f32_16x16x32_f16(af[m], bf[n], acc[m][n], 0, 0, 0);

    if (more) {
      const int nxt = cur ^ 1;
      half8 ah;
#pragma unroll
      for (int e = 0; e < 4; ++e) { ah[e] = (_Float16)a0[e]; ah[e + 4] = (_Float16)a1[e]; }
#pragma unroll
      for (int q = 0; q < 4; ++q) *(half8*)(&Blds[nxt][0] + q * 4096 + tid * 8) = bs[q];
      *(half8*)(&Alds[nxt][0][0] + awr_off) = ah;
    }
    __syncthreads();
  }

  // ---- epilogue: bias, var=exp(2*ls), z = mean + sqrt(var)*eps
  // LDS-transposed full-line writes: per m-block, dump [32 rows][256 cols]
  // (rows = both wave-row bands) into padded float[32][260], then each wave
  // stores one full 1KB output row per float4-store instruction.
  float* ebuf = (float*)(&Blds[0][0]);            // 32*260*4 = 33.3 KiB
  float* out_mean = out;
  float* out_var  = out + (size_t)N_ROWS * J_OUT;
  float* out_z    = out + 2 * (size_t)N_ROWS * J_OUT;
  const int colq = lane & 15;
  const int g4   = (lane >> 4) * 4;               // row-in-16 base
  const int lrow  = wr * 16 + g4;                 // LDS row (+e)
  const int lcolb = wc * 64 + colq;               // LDS col (+q*16)

#pragma unroll
  for (int m = 0; m < 4; ++m) {
    float mv[16], vv[16], zv[16];
#pragma unroll
    for (int q = 0; q < 4; ++q) {
      const int c = wc * 64 + q * 16 + colq;      // output column 0..255
      const float bm = b_mu[c];
      const float bl = b_ls[c];
      const int rabs = rowbase + wr * 64 + m * 16 + g4;
#pragma unroll
      for (int e = 0; e < 4; ++e) {
        const float mean = acc[m][2 * q][e] + bm;
        const float ls   = acc[m][2 * q + 1][e] + bl;
        const float var  = __expf(2.0f * ls);
        const uint32_t bits = tf_bits_xor((uint32_t)((rabs + e) * J_OUT + c));
        mv[q * 4 + e] = mean;
        vv[q * 4 + e] = var;
        zv[q * 4 + e] = fmaf(sqrtf(var), eps_from_bits(bits), mean);
      }
    }
#pragma unroll
    for (int arr = 0; arr < 3; ++arr) {
      __syncthreads();                            // prior round's reads done
#pragma unroll
      for (int q = 0; q < 4; ++q)
#pragma unroll
        for (int e = 0; e < 4; ++e) {
          const float v = (arr == 0) ? mv[q * 4 + e]
                        : (arr == 1) ? vv[q * 4 + e] : zv[q * 4 + e];
          ebuf[(lrow + e) * 260 + lcolb + q * 16] = v;
        }
      __syncthreads();
      float* oarr = (arr == 0) ? out_mean : (arr == 1) ? out_var : out_z;
#pragma unroll
      for (int i = 0; i < 4; ++i) {
        const int idx = i * THREADS + tid;        // 0..2047
        const int r  = idx >> 6;                  // 0..31
        const int c4 = idx & 63;                  // float4 index in row
        const f32x4 v = *(const f32x4*)(ebuf + r * 260 + c4 * 4);
        const int band = r >> 4, rr = r & 15;
        const size_t orow = (size_t)(rowbase + band * 64 + m * 16 + rr);
        *(f32x4*)(oarr + orow * J_OUT + c4 * 4) = v;
      }
    }
  }
}

extern "C" void kernel_launch(void* const* d_in, const int* in_sizes, int n_in,
                              void* d_out, int out_size, void* d_ws, size_t ws_size,
                              hipStream_t stream) {
  const float* x   = (const float*)d_in[0];
  const float* Wmu = (const float*)d_in[1];
  const float* bmu = (const float*)d_in[2];
  const float* Wls = (const float*)d_in[3];
  const float* bls = (const float*)d_in[4];
  float* out = (float*)d_out;
  _Float16* wt = (_Float16*)d_ws;   // needs 1 MiB scratch

  pack_w_kernel<<<256, 256, 0, stream>>>(Wmu, Wls, wt);
  fused_heads_kernel<<<N_ROWS / BM, THREADS, 0, stream>>>(x, wt, bmu, bls, out);
}

// Round 7
// 354.238 us; speedup vs baseline: 4.7425x; 4.7425x over previous
//
#include <hip/hip_runtime.h>
#include <stdint.h>

#define N_ROWS 65536
#define K_DIM  1024
#define J_OUT  256
#define BM 128
#define NT 32             // K-steps of 32
#define THREADS 512       // 8 waves: 2 wave-rows x 4 wave-cols

typedef _Float16 half8 __attribute__((ext_vector_type(8)));
typedef float    f32x4 __attribute__((ext_vector_type(4)));

// ---------------- threefry2x32, key=(0,42) — partitionable, XOR-fold -------
// bits = b1 ^ b2 of threefry2x32(k1=0,k2=42, x0=0, x1=i).  (Verified R5.)
__device__ __forceinline__ uint32_t tf_bits_xor(uint32_t ctr) {
  const uint32_t ks0 = 0u, ks1 = 42u, ks2 = 0x1BD11BF0u;
  uint32_t x0 = 0u;
  uint32_t x1 = ctr + ks1;
#define TF_R(rr) x0 += x1; x1 = ((x1 << rr) | (x1 >> (32 - rr))) ^ x0;
  TF_R(13) TF_R(15) TF_R(26) TF_R(6)
  x0 += ks1; x1 += ks2 + 1u;
  TF_R(17) TF_R(29) TF_R(16) TF_R(24)
  x0 += ks2; x1 += ks0 + 2u;
  TF_R(13) TF_R(15) TF_R(26) TF_R(6)
  x0 += ks0; x1 += ks1 + 3u;
  TF_R(17) TF_R(29) TF_R(16) TF_R(24)
  x0 += ks1; x1 += ks2 + 4u;
  TF_R(13) TF_R(15) TF_R(26) TF_R(6)
  x0 += ks2; x1 += ks0 + 5u;
#undef TF_R
  return x0 ^ x1;
}

// uniform(lo=nextafter(-1,0),hi=1) then sqrt(2)*erfinv (XLA Giles). Verified R5.
__device__ __forceinline__ float eps_from_bits(uint32_t bits) {
  float f = __uint_as_float((bits >> 9) | 0x3F800000u) - 1.0f;
  float u = fmaxf(-0.99999994f, f * 2.0f - 0.99999994f);
  float w = -log1pf(-u * u);
  float p;
  if (w < 5.0f) {
    w = w - 2.5f;
    p = 2.81022636e-08f;
    p = fmaf(p, w, 3.43273939e-07f);
    p = fmaf(p, w, -3.5233877e-06f);
    p = fmaf(p, w, -4.39150654e-06f);
    p = fmaf(p, w, 0.00021858087f);
    p = fmaf(p, w, -0.00125372503f);
    p = fmaf(p, w, -0.00417768164f);
    p = fmaf(p, w, 0.246640727f);
    p = fmaf(p, w, 1.50140941f);
  } else {
    w = sqrtf(w) - 3.0f;
    p = -0.000200214257f;
    p = fmaf(p, w, 0.000100950558f);
    p = fmaf(p, w, 0.00134934322f);
    p = fmaf(p, w, -0.00367342844f);
    p = fmaf(p, w, 0.00573950773f);
    p = fmaf(p, w, -0.0076224613f);
    p = fmaf(p, w, -0.00943887047f);
    p = fmaf(p, w, 1.00167406f);
    p = fmaf(p, w, 2.83297682f);
  }
  return 1.41421354f * (p * u);
}

// ---------------- W pre-pack: f32 -> f16 in MFMA B-fragment order ----------
// halves index = ((t*512 + j)*4 + g)*8 + e  holds  W_head[j][k = t*32+g*8+e][c]
//   j = 0..511: head h=(j>>4)&1 (0=mu,1=log_std), col c = (j>>5)*16 + (j&15)
// So bf[n] for wave-col wc, lane l is ONE dwordx4 at
//   wt + (t*512 + wc*128 + n*16 + (l&15))*32 + (l>>4)*8.
__global__ void pack_w_kernel(const float* __restrict__ Wmu,
                              const float* __restrict__ Wls,
                              _Float16* __restrict__ wt) {
  const int chunk = blockIdx.x * blockDim.x + threadIdx.x;  // 0..65535
  const int g = chunk & 3;
  const int j = (chunk >> 2) & 511;
  const int t = chunk >> 11;
  const int k0 = t * 32 + g * 8;
  const int h = (j >> 4) & 1;
  const int c = ((j >> 5) << 4) | (j & 15);
  const float* W = h ? Wls : Wmu;
  half8 v;
#pragma unroll
  for (int e = 0; e < 8; ++e) v[e] = (_Float16)W[(size_t)(k0 + e) * J_OUT + c];
  *(half8*)(wt + (size_t)chunk * 8) = v;
}

// ---------------- fused GEMM + heads + sampling ----------------------------
// No LDS in the K-loop, no barriers, no staging registers: A fragments read
// directly from x (+in-reg f16 cvt), B fragments read directly from packed wt.
__global__ __launch_bounds__(THREADS, 2)
void fused_heads_kernel(const float* __restrict__ x,
                        const _Float16* __restrict__ wt,
                        const float* __restrict__ b_mu,
                        const float* __restrict__ b_ls,
                        float* __restrict__ out) {
  __shared__ __align__(16) float ebuf[32 * 260];   // epilogue transpose, 33.3 KiB
  const int tid  = threadIdx.x;
  const int lane = tid & 63;
  const int wv   = tid >> 6;        // wave 0..7
  const int wr   = wv >> 2;         // wave row 0..1 (64 output rows each)
  const int wc   = wv & 3;          // wave col 0..3 (64 fused cols each)
  const int rowbase = blockIdx.x * BM;

  // A: lane (r=lane&15, g=lane>>4) reads x[row0 + m*16][t*32 + g*8 .. +8]
  const float* aBase = x + (size_t)(rowbase + wr * 64 + (lane & 15)) * K_DIM
                         + (lane >> 4) * 8;
  // B: lane (c=lane&15, g=lane>>4) reads frag n at bBase + t*16384 + n*512
  const _Float16* bBase = wt + ((size_t)(wc * 128 + (lane & 15)) * 32
                                + (lane >> 4) * 8);

  f32x4 acc[4][8] = {};

#pragma unroll 2
  for (int t = 0; t < NT; ++t) {
    const float* ap = aBase + t * 32;
    const _Float16* bp = bBase + (size_t)t * 16384;
    half8 af[4], bf[8];
#pragma unroll
    for (int m = 0; m < 4; ++m) {
      const f32x4 lo = *(const f32x4*)(ap + (size_t)m * 16 * K_DIM);
      const f32x4 hi = *(const f32x4*)(ap + (size_t)m * 16 * K_DIM + 4);
#pragma unroll
      for (int e = 0; e < 4; ++e) { af[m][e] = (_Float16)lo[e]; af[m][e + 4] = (_Float16)hi[e]; }
    }
#pragma unroll
    for (int n = 0; n < 8; ++n) bf[n] = *(const half8*)(bp + n * 512);
#pragma unroll
    for (int m = 0; m < 4; ++m)
#pragma unroll
      for (int n = 0; n < 8; ++n)
        acc[m][n] = __builtin_amdgcn_mfma_f32_16x16x32_f16(af[m], bf[n], acc[m][n], 0, 0, 0);
  }

  // ---- epilogue: bias, var=exp(2*ls), z = mean + sqrt(var)*eps
  // LDS-transposed full-line writes (passed R6): per m-block, dump
  // [32 rows][256 cols] into padded float[32][260], then 16B stores cover
  // each 1KB output row contiguously.
  float* out_mean = out;
  float* out_var  = out + (size_t)N_ROWS * J_OUT;
  float* out_z    = out + 2 * (size_t)N_ROWS * J_OUT;
  const int colq = lane & 15;
  const int g4   = (lane >> 4) * 4;
  const int lrow  = wr * 16 + g4;
  const int lcolb = wc * 64 + colq;

#pragma unroll
  for (int m = 0; m < 4; ++m) {
    float mv[16], vv[16], zv[16];
#pragma unroll
    for (int q = 0; q < 4; ++q) {
      const int c = wc * 64 + q * 16 + colq;
      const float bm = b_mu[c];
      const float bl = b_ls[c];
      const int rabs = rowbase + wr * 64 + m * 16 + g4;
#pragma unroll
      for (int e = 0; e < 4; ++e) {
        const float mean = acc[m][2 * q][e] + bm;
        const float ls   = acc[m][2 * q + 1][e] + bl;
        const float var  = __expf(2.0f * ls);
        const uint32_t bits = tf_bits_xor((uint32_t)((rabs + e) * J_OUT + c));
        mv[q * 4 + e] = mean;
        vv[q * 4 + e] = var;
        zv[q * 4 + e] = fmaf(sqrtf(var), eps_from_bits(bits), mean);
      }
    }
#pragma unroll
    for (int arr = 0; arr < 3; ++arr) {
      __syncthreads();
#pragma unroll
      for (int q = 0; q < 4; ++q)
#pragma unroll
        for (int e = 0; e < 4; ++e) {
          const float v = (arr == 0) ? mv[q * 4 + e]
                        : (arr == 1) ? vv[q * 4 + e] : zv[q * 4 + e];
          ebuf[(lrow + e) * 260 + lcolb + q * 16] = v;
        }
      __syncthreads();
      float* oarr = (arr == 0) ? out_mean : (arr == 1) ? out_var : out_z;
#pragma unroll
      for (int i = 0; i < 4; ++i) {
        const int idx = i * THREADS + tid;        // 0..2047
        const int r  = idx >> 6;                  // 0..31
        const int c4 = idx & 63;                  // float4 index in row
        const f32x4 v = *(const f32x4*)(ebuf + r * 260 + c4 * 4);
        const int band = r >> 4, rr = r & 15;
        const size_t orow = (size_t)(rowbase + band * 64 + m * 16 + rr);
        *(f32x4*)(oarr + orow * J_OUT + c4 * 4) = v;
      }
    }
  }
}

extern "C" void kernel_launch(void* const* d_in, const int* in_sizes, int n_in,
                              void* d_out, int out_size, void* d_ws, size_t ws_size,
                              hipStream_t stream) {
  const float* x   = (const float*)d_in[0];
  const float* Wmu = (const float*)d_in[1];
  const float* bmu = (const float*)d_in[2];
  const float* Wls = (const float*)d_in[3];
  const float* bls = (const float*)d_in[4];
  float* out = (float*)d_out;
  _Float16* wt = (_Float16*)d_ws;   // 1 MiB scratch

  pack_w_kernel<<<256, 256, 0, stream>>>(Wmu, Wls, wt);
  fused_heads_kernel<<<N_ROWS / BM, THREADS, 0, stream>>>(x, wt, bmu, bls, out);
}